// Round 3
// baseline (681.309 us; speedup 1.0000x reference)
//
#include <hip/hip_runtime.h>
#include <math.h>

#define BATCH 256
#define FEAT 128
#define CAP 100000
#define HORIZON 24
#define NFEAT 7
#define ROWF (HORIZON*NFEAT)   // 168
#define K 5
#define CHUNK 200
#define NCHUNK 500             // CHUNK*NCHUNK == CAP exactly
#define NCAND (NCHUNK*K)       // 2500
#define CPT 10                 // ceil(NCAND/256)

// out layout (floats): retrieved [0,215040) | top_sims [215040,216320)
//                      valid_mask [216320,217600) | top_idx [217600,218880)
#define OUT_SIMS 215040
#define OUT_MASK 216320
#define OUT_IDX  217600

// ws layout (4-byte elems):
#define WS_QN    0        // 256*128 floats, row-major normalized queries
#define WS_SCALE 32768    // 100000 floats
#define WS_PSIM  132768   // BATCH*NCAND = 640000 floats, [q][2500]
#define WS_PIDX  772768   // 640000 ints,   [q][2500]

__global__ __launch_bounds__(64) void qnorm_kernel(const float* __restrict__ q,
                                                   float* __restrict__ qn) {
  int b = blockIdx.x;
  int l = threadIdx.x;
  float2 v = reinterpret_cast<const float2*>(q + (size_t)b*FEAT)[l];
  float ss = v.x*v.x + v.y*v.y;
  #pragma unroll
  for (int o = 1; o < 64; o <<= 1) ss += __shfl_xor(ss, o);
  float inv = 1.0f / fmaxf(sqrtf(ss), 1e-12f);
  float2 w; w.x = v.x*inv; w.y = v.y*inv;
  reinterpret_cast<float2*>(qn + (size_t)b*FEAT)[l] = w;
}

__global__ __launch_bounds__(256) void kscale_kernel(const float* __restrict__ keys,
                                                     const int* __restrict__ ts,
                                                     const int* __restrict__ gstep,
                                                     float* __restrict__ scale) {
  int gid  = blockIdx.x*blockDim.x + threadIdx.x;
  int key  = gid >> 6;
  int lane = threadIdx.x & 63;
  if (key >= CAP) return;
  float2 v = reinterpret_cast<const float2*>(keys + (size_t)key*FEAT)[lane];
  float ss = v.x*v.x + v.y*v.y;
  #pragma unroll
  for (int o = 1; o < 64; o <<= 1) ss += __shfl_xor(ss, o);
  if (lane == 0) {
    float age = (float)(gstep[0] - ts[key]);
    float decay = powf(0.995f, age);
    scale[key] = decay / fmaxf(sqrtf(ss), 1e-12f);
  }
}

__device__ __forceinline__ void topk_insert(float sim, int k,
    float& s0, float& s1, float& s2, float& s3, float& s4,
    int& i0, int& i1, int& i2, int& i3, int& i4) {
  // streaming ascending k + strict '>' == jax tie-break (lower idx first)
  if (sim > s4) {
    if (sim > s3) {
      s4=s3; i4=i3;
      if (sim > s2) {
        s3=s2; i3=i2;
        if (sim > s1) {
          s2=s1; i2=i1;
          if (sim > s0) { s1=s0; i1=i0; s0=sim; i0=k; }
          else          { s1=sim; i1=k; }
        } else { s2=sim; i2=k; }
      } else { s3=sim; i3=k; }
    } else { s4=sim; i4=k; }
  }
}

// K-split: lane = s*16 + qlane; s = feature-slice (32 dims), 16 queries/wave.
// Block 512 thr = 8 waves = 128 queries; grid = NCHUNK * 2 query-groups.
__global__ __launch_bounds__(512) void sim_topk_kernel(
    const float* __restrict__ keys,
    const float* __restrict__ qn,      // [256][128] row-major, normalized
    const float* __restrict__ scale,
    float* __restrict__ psim,          // [q][NCAND]
    int* __restrict__ pidx) {
  int t    = threadIdx.x;
  int wv   = t >> 6;            // wave 0..7
  int lane = t & 63;
  int s    = lane >> 4;         // feature slice 0..3
  int ql   = lane & 15;         // query-in-wave
  int chunk = blockIdx.x >> 1;
  int qg    = blockIdx.x & 1;
  int q     = qg*128 + wv*16 + ql;
  int k0    = chunk * CHUNK;

  // 32 query floats per thread, constant-indexed -> stays in 32 VGPRs
  float4 qv[8];
  const float4* qp = reinterpret_cast<const float4*>(qn + (size_t)q*FEAT + s*32);
  #pragma unroll
  for (int d = 0; d < 8; ++d) qv[d] = qp[d];

  float s0=-INFINITY, s1=-INFINITY, s2=-INFINITY, s3=-INFINITY, s4=-INFINITY;
  int   i0=0, i1=0, i2=0, i3=0, i4=0;

  for (int k = k0; k < k0 + CHUNK; k += 2) {
    const float4* ka = reinterpret_cast<const float4*>(keys + (size_t)k*FEAT + s*32);
    const float4* kb = ka + 32;   // next key row, same slice
    float a0=0.f, a1=0.f, a2=0.f, a3=0.f;
    float b0=0.f, b1=0.f, b2=0.f, b3=0.f;
    #pragma unroll
    for (int d = 0; d < 8; ++d) {
      float4 va = ka[d];
      float4 vb = kb[d];
      float4 qd = qv[d];
      a0 = fmaf(va.x, qd.x, a0);
      a1 = fmaf(va.y, qd.y, a1);
      a2 = fmaf(va.z, qd.z, a2);
      a3 = fmaf(va.w, qd.w, a3);
      b0 = fmaf(vb.x, qd.x, b0);
      b1 = fmaf(vb.y, qd.y, b1);
      b2 = fmaf(vb.z, qd.z, b2);
      b3 = fmaf(vb.w, qd.w, b3);
    }
    float sa = (a0+a1)+(a2+a3);
    float sb = (b0+b1)+(b2+b3);
    // combine the 4 feature slices: all lanes end with the full dot
    sa += __shfl_xor(sa, 16);  sa += __shfl_xor(sa, 32);
    sb += __shfl_xor(sb, 16);  sb += __shfl_xor(sb, 32);
    float simA = sa * scale[k];
    float simB = sb * scale[k+1];
    topk_insert(simA, k,   s0,s1,s2,s3,s4, i0,i1,i2,i3,i4);
    topk_insert(simB, k+1, s0,s1,s2,s3,s4, i0,i1,i2,i3,i4);
  }

  if (s == 0) {   // one writer per query
    int base = q*NCAND + chunk*K;
    psim[base+0]=s0; psim[base+1]=s1; psim[base+2]=s2; psim[base+3]=s3; psim[base+4]=s4;
    pidx[base+0]=i0; pidx[base+1]=i1; pidx[base+2]=i2; pidx[base+3]=i3; pidx[base+4]=i4;
  }
}

__global__ __launch_bounds__(256) void merge_kernel(const float* __restrict__ psim,
                                                    const int* __restrict__ pidx,
                                                    const float* __restrict__ values,
                                                    float* __restrict__ out) {
  int q = blockIdx.x;
  int t = threadIdx.x;

  float cs[CPT]; int ci[CPT];
  #pragma unroll
  for (int j = 0; j < CPT; ++j) {
    int c = t + j*256;            // coalesced: [q][c]
    if (c < NCAND) {
      cs[j] = psim[q*NCAND + c];
      ci[j] = pidx[q*NCAND + c];
    } else { cs[j] = -INFINITY; ci[j] = 0x7fffffff; }
  }

  __shared__ float lds_s[4];
  __shared__ int   lds_i[4];
  __shared__ float win_s;
  __shared__ int   win_i;

  unsigned taken = 0;
  for (int r = 0; r < K; ++r) {
    float bs = -INFINITY; int bi = 0x7fffffff;
    #pragma unroll
    for (int j = 0; j < CPT; ++j) {
      bool live = !((taken >> j) & 1u);
      bool bet  = live && (cs[j] > bs || (cs[j] == bs && ci[j] < bi));
      bs = bet ? cs[j] : bs;
      bi = bet ? ci[j] : bi;
    }
    #pragma unroll
    for (int o = 1; o < 64; o <<= 1) {
      float os = __shfl_xor(bs, o);
      int   oi = __shfl_xor(bi, o);
      if (os > bs || (os == bs && oi < bi)) { bs = os; bi = oi; }
    }
    int w = t >> 6;
    if ((t & 63) == 0) { lds_s[w] = bs; lds_i[w] = bi; }
    __syncthreads();
    if (t == 0) {
      float fs = lds_s[0]; int fi = lds_i[0];
      #pragma unroll
      for (int ww = 1; ww < 4; ++ww) {
        float os = lds_s[ww]; int oi = lds_i[ww];
        if (os > fs || (os == fs && oi < fi)) { fs = os; fi = oi; }
      }
      win_s = fs; win_i = fi;
      out[OUT_SIMS + q*K + r] = fs;
      out[OUT_MASK + q*K + r] = (fs >= 0.0f) ? 1.0f : 0.0f;
      out[OUT_IDX  + q*K + r] = (float)fi;
    }
    __syncthreads();
    int fi = win_i;
    #pragma unroll
    for (int j = 0; j < CPT; ++j) if (ci[j] == fi) taken |= (1u << j);
    for (int e = t; e < ROWF; e += 256)
      out[(q*K + r)*ROWF + e] = values[(size_t)fi*ROWF + e];
    __syncthreads();
  }
}

extern "C" void kernel_launch(void* const* d_in, const int* in_sizes, int n_in,
                              void* d_out, int out_size, void* d_ws, size_t ws_size,
                              hipStream_t stream) {
  const float* query  = (const float*)d_in[0];
  const float* keys   = (const float*)d_in[1];
  const float* values = (const float*)d_in[2];
  const int*   ts     = (const int*)d_in[3];
  const int*   gstep  = (const int*)d_in[4];

  float* out  = (float*)d_out;
  float* wsf  = (float*)d_ws;
  int*   wsi  = (int*)d_ws;

  float* qn    = wsf + WS_QN;
  float* scale = wsf + WS_SCALE;
  float* psim  = wsf + WS_PSIM;
  int*   pidx  = wsi + WS_PIDX;

  qnorm_kernel<<<BATCH, 64, 0, stream>>>(query, qn);
  kscale_kernel<<<(CAP*64 + 255)/256, 256, 0, stream>>>(keys, ts, gstep, scale);
  sim_topk_kernel<<<NCHUNK*2, 512, 0, stream>>>(keys, qn, scale, psim, pidx);
  merge_kernel<<<BATCH, 256, 0, stream>>>(psim, pidx, values, out);
}

// Round 4
// 80.164 us; speedup vs baseline: 8.4989x; 8.4989x over previous
//
#include <hip/hip_runtime.h>
#include <math.h>

#define BATCH 256
#define FEAT 128
#define CAP 100000
#define ROWF 168
#define K 5
#define CHUNKK 256
#define NBLK 391            // 391*256 = 100096 >= CAP
#define NCAND (NBLK*K)      // 1955
#define CPT 8               // ceil(1955/256)

// out layout (floats): retrieved [0,215040) | top_sims | valid_mask | top_idx
#define OUT_SIMS 215040
#define OUT_MASK 216320
#define OUT_IDX  217600

// ws layout (float units)
#define WS_QN    0          // 256*128 f32 normalized queries (exact rescore)
#define WS_QF    32768      // 4096 uint4 = bf16 B-fragments
#define WS_PSIM  49152      // 256*1955 f32
#define WS_PIDX  549632     // 256*1955 i32

typedef __attribute__((ext_vector_type(8))) short short8;
typedef __attribute__((ext_vector_type(4))) float f32x4;

#define BET(vs,vi,ss,ii) ((vs) > (ss) || ((vs) == (ss) && (vi) < (ii)))

__device__ __forceinline__ unsigned short f2bf(float f) {
  unsigned u = __float_as_uint(f);
  u += 0x7fffu + ((u >> 16) & 1u);     // RNE
  return (unsigned short)(u >> 16);
}
__device__ __forceinline__ unsigned pack2(float a, float b) {
  return (unsigned)f2bf(a) | ((unsigned)f2bf(b) << 16);
}

__device__ __forceinline__ void ins_stream(float v, int k, float (&s)[5], int (&i)[5]) {
  // stream arrives in ascending idx; strict '>' == jax tie-break (lower idx first)
  if (v > s[4]) {
    if (v > s[3]) { s[4]=s[3]; i[4]=i[3];
      if (v > s[2]) { s[3]=s[2]; i[3]=i[2];
        if (v > s[1]) { s[2]=s[1]; i[2]=i[1];
          if (v > s[0]) { s[1]=s[0]; i[1]=i[0]; s[0]=v; i[0]=k; }
          else { s[1]=v; i[1]=k; } }
        else { s[2]=v; i[2]=k; } }
      else { s[3]=v; i[3]=k; } }
    else { s[4]=v; i[4]=k; }
  }
}
__device__ __forceinline__ void ins_cmp(float v, int k, float (&s)[5], int (&i)[5]) {
  if (BET(v,k,s[4],i[4])) {
    if (BET(v,k,s[3],i[3])) { s[4]=s[3]; i[4]=i[3];
      if (BET(v,k,s[2],i[2])) { s[3]=s[2]; i[3]=i[2];
        if (BET(v,k,s[1],i[1])) { s[2]=s[1]; i[2]=i[1];
          if (BET(v,k,s[0],i[0])) { s[1]=s[0]; i[1]=i[0]; s[0]=v; i[0]=k; }
          else { s[1]=v; i[1]=k; } }
        else { s[2]=v; i[2]=k; } }
      else { s[3]=v; i[3]=k; } }
    else { s[4]=v; i[4]=k; }
  }
}

// grid 16 (q-groups of 16), block 256. Writes f32 qn + bf16 B-fragments.
__global__ __launch_bounds__(256) void prep_q(const float* __restrict__ q,
                                              float* __restrict__ qn,
                                              uint4* __restrict__ qF) {
  int tid = threadIdx.x, qg = blockIdx.x;
  int qi = tid >> 4;             // query in group (0..15)
  int d0 = (tid & 15) * 8;
  int q_ = qg*16 + qi;
  const float4* src = reinterpret_cast<const float4*>(q + (size_t)q_*FEAT + d0);
  float4 v0 = src[0], v1 = src[1];
  float ss = v0.x*v0.x + v0.y*v0.y + v0.z*v0.z + v0.w*v0.w
           + v1.x*v1.x + v1.y*v1.y + v1.z*v1.z + v1.w*v1.w;
  ss += __shfl_xor(ss,1); ss += __shfl_xor(ss,2);
  ss += __shfl_xor(ss,4); ss += __shfl_xor(ss,8);
  float inv = 1.0f / fmaxf(sqrtf(ss), 1e-12f);
  v0.x*=inv; v0.y*=inv; v0.z*=inv; v0.w*=inv;
  v1.x*=inv; v1.y*=inv; v1.z*=inv; v1.w*=inv;
  float4* dst = reinterpret_cast<float4*>(qn + (size_t)q_*FEAT + d0);
  dst[0] = v0; dst[1] = v1;
  uint4 pk;
  pk.x = pack2(v0.x,v0.y); pk.y = pack2(v0.z,v0.w);
  pk.z = pack2(v1.x,v1.y); pk.w = pack2(v1.z,v1.w);
  // B-frag: col=lane&15 (query), k=(lane>>4)*8+e ; d = s*32 + (lane>>4)*8 + e
  int s_ = d0 >> 5, lg = (d0 >> 3) & 3;
  qF[((qg*4 + s_)*64) + lg*16 + qi] = pk;
}

// grid NBLK, block 512 (8 waves; wave w owns query-groups 2w, 2w+1)
__global__ __launch_bounds__(512, 2) void gemm_topk(
    const float* __restrict__ keys, const int* __restrict__ ts,
    const int* __restrict__ gstep, const uint4* __restrict__ qF,
    float* __restrict__ psim, int* __restrict__ pidx) {
  __shared__ uint4 lds_kb[2*2*4*64];   // [buf][tile16][s][lane], 16 KB
  int tid = threadIdx.x;
  int w = tid >> 6, lane = tid & 63;
  int kbase = blockIdx.x * CHUNKK;
  int gstep0 = gstep[0];

  short8 qf0[4], qf1[4];
  #pragma unroll
  for (int s_=0; s_<4; ++s_) {
    uint4 a = qF[((2*w  )*4 + s_)*64 + lane];
    uint4 b = qF[((2*w+1)*4 + s_)*64 + lane];
    qf0[s_] = __builtin_bit_cast(short8, a);
    qf1[s_] = __builtin_bit_cast(short8, b);
  }

  float ts0[5] = {-INFINITY,-INFINITY,-INFINITY,-INFINITY,-INFINITY};
  float ts1[5] = {-INFINITY,-INFINITY,-INFINITY,-INFINITY,-INFINITY};
  int   ti0[5] = {0,0,0,0,0}, ti1[5] = {0,0,0,0,0};

  auto stage = [&](int p, int buf) {
    int key32 = tid >> 4;             // 0..31 (two 16-key tiles)
    int d0 = (tid & 15) * 8;
    int gk = kbase + p*32 + key32;
    float4 v0 = {0,0,0,0}, v1 = {0,0,0,0};
    if (gk < CAP) {
      const float4* kp = reinterpret_cast<const float4*>(keys + (size_t)gk*FEAT + d0);
      v0 = kp[0]; v1 = kp[1];
    }
    float ss = v0.x*v0.x+v0.y*v0.y+v0.z*v0.z+v0.w*v0.w
             + v1.x*v1.x+v1.y*v1.y+v1.z*v1.z+v1.w*v1.w;
    ss += __shfl_xor(ss,1); ss += __shfl_xor(ss,2);
    ss += __shfl_xor(ss,4); ss += __shfl_xor(ss,8);
    float scl = 0.0f;
    if (gk < CAP) {
      float age = (float)(gstep0 - ts[gk]);
      float decay = exp2f(age * -0.00723157f);   // 0.995^age (approx path only)
      scl = decay / fmaxf(sqrtf(ss), 1e-12f);
    }
    uint4 pk;
    pk.x = pack2(v0.x*scl, v0.y*scl); pk.y = pack2(v0.z*scl, v0.w*scl);
    pk.z = pack2(v1.x*scl, v1.y*scl); pk.w = pack2(v1.z*scl, v1.w*scl);
    int tt = key32 >> 4, k15 = key32 & 15;
    int s_ = d0 >> 5, lg = (d0 >> 3) & 3;
    lds_kb[((buf*2 + tt)*4 + s_)*64 + lg*16 + k15] = pk;
  };

  stage(0, 0);
  __syncthreads();
  int buf = 0;
  for (int p = 0; p < 8; ++p) {
    if (p < 7) stage(p+1, buf^1);
    #pragma unroll
    for (int tt = 0; tt < 2; ++tt) {
      f32x4 acc0 = {0.f,0.f,0.f,0.f}, acc1 = {0.f,0.f,0.f,0.f};
      #pragma unroll
      for (int s_=0; s_<4; ++s_) {
        uint4 au = lds_kb[((buf*2+tt)*4 + s_)*64 + lane];
        short8 a = __builtin_bit_cast(short8, au);
        acc0 = __builtin_amdgcn_mfma_f32_16x16x32_bf16(a, qf0[s_], acc0, 0,0,0);
        acc1 = __builtin_amdgcn_mfma_f32_16x16x32_bf16(a, qf1[s_], acc1, 0,0,0);
      }
      // C/D: col=lane&15 (query), row=(lane>>4)*4+r (key) [verified layout]
      int kb = kbase + p*32 + tt*16 + (lane>>4)*4;
      #pragma unroll
      for (int r=0;r<4;++r) ins_stream(acc0[r], kb + r, ts0, ti0);
      #pragma unroll
      for (int r=0;r<4;++r) ins_stream(acc1[r], kb + r, ts1, ti1);
    }
    __syncthreads();
    buf ^= 1;
  }

  // merge the 4 lane-groups (each saw a distinct key subset) for each query col
  #pragma unroll
  for (int off = 16; off <= 32; off <<= 1) {
    float ps[5]; int pi[5];
    #pragma unroll
    for (int j=0;j<5;++j){ ps[j]=__shfl_xor(ts0[j],off); pi[j]=__shfl_xor(ti0[j],off); }
    #pragma unroll
    for (int j=0;j<5;++j) ins_cmp(ps[j], pi[j], ts0, ti0);
    #pragma unroll
    for (int j=0;j<5;++j){ ps[j]=__shfl_xor(ts1[j],off); pi[j]=__shfl_xor(ti1[j],off); }
    #pragma unroll
    for (int j=0;j<5;++j) ins_cmp(ps[j], pi[j], ts1, ti1);
  }

  if (lane < 16) {
    int q0 = (2*w)*16 + lane;
    int q1 = (2*w+1)*16 + lane;
    int b0 = q0*NCAND + blockIdx.x*K;
    int b1 = q1*NCAND + blockIdx.x*K;
    #pragma unroll
    for (int j=0;j<K;++j) {
      psim[b0+j]=ts0[j]; pidx[b0+j]=ti0[j];
      psim[b1+j]=ts1[j]; pidx[b1+j]=ti1[j];
    }
  }
}

// grid 256 (1/query), block 256: approx top-5 -> margin filter -> exact rescore
__global__ __launch_bounds__(256) void merge_rescore(
    const float* __restrict__ psim, const int* __restrict__ pidx,
    const float* __restrict__ keys, const float* __restrict__ qn,
    const int* __restrict__ ts, const int* __restrict__ gstep,
    const float* __restrict__ values, float* __restrict__ out) {
  int q = blockIdx.x, tid = threadIdx.x;
  int gstep0 = gstep[0];
  float cs[CPT]; int ci[CPT];
  #pragma unroll
  for (int j=0;j<CPT;++j) {
    int c = tid + j*256;
    if (c < NCAND) { cs[j]=psim[q*NCAND+c]; ci[j]=pidx[q*NCAND+c]; }
    else { cs[j]=-INFINITY; ci[j]=0x7fffffff; }
  }

  __shared__ float rs_[4]; __shared__ int ri_[4];
  __shared__ float wS; __shared__ int wI;
  unsigned taken = 0;
  float s5a = 0.f;
  for (int r=0;r<K;++r) {
    float bs=-INFINITY; int bi=0x7fffffff;
    #pragma unroll
    for (int j=0;j<CPT;++j) {
      bool live = !((taken>>j)&1u);
      bool bet = live && BET(cs[j],ci[j],bs,bi);
      bs = bet?cs[j]:bs; bi = bet?ci[j]:bi;
    }
    #pragma unroll
    for (int o=1;o<64;o<<=1) {
      float os=__shfl_xor(bs,o); int oi=__shfl_xor(bi,o);
      if (BET(os,oi,bs,bi)) { bs=os; bi=oi; }
    }
    if ((tid&63)==0){ rs_[tid>>6]=bs; ri_[tid>>6]=bi; }
    __syncthreads();
    if (tid==0) {
      float fs=rs_[0]; int fi=ri_[0];
      #pragma unroll
      for (int ww=1;ww<4;++ww) if (BET(rs_[ww],ri_[ww],fs,fi)) { fs=rs_[ww]; fi=ri_[ww]; }
      wS=fs; wI=fi;
    }
    __syncthreads();
    float fs=wS; int fi=wI;
    #pragma unroll
    for (int j=0;j<CPT;++j) if (ci[j]==fi) taken |= (1u<<j);
    if (r==K-1) s5a = fs;
  }

  // collect everything within margin of the 5th approx (bf16 err << 8e-3)
  float thresh = s5a - 0.008f;
  __shared__ int cnt; __shared__ int clx[32];
  if (tid==0) cnt=0;
  __syncthreads();
  #pragma unroll
  for (int j=0;j<CPT;++j)
    if (cs[j] >= thresh) { int p = atomicAdd(&cnt,1); if (p<32) clx[p]=ci[j]; }
  __syncthreads();
  int m = cnt; if (m>32) m=32;

  // exact f32 rescore (same arithmetic as reference path)
  __shared__ float exs[32];
  int wv = tid>>6, lane = tid&63;
  for (int c=wv; c<m; c+=4) {
    int idx = clx[c];
    float dot=0.f, ksq=0.f;
    if (idx < CAP) {
      float2 kv = reinterpret_cast<const float2*>(keys + (size_t)idx*FEAT)[lane];
      float2 qv = reinterpret_cast<const float2*>(qn  + (size_t)q  *FEAT)[lane];
      dot = kv.x*qv.x + kv.y*qv.y;
      ksq = kv.x*kv.x + kv.y*kv.y;
    }
    #pragma unroll
    for (int o=1;o<64;o<<=1){ dot += __shfl_xor(dot,o); ksq += __shfl_xor(ksq,o); }
    if (lane==0) {
      float sim = -INFINITY;
      if (idx < CAP) {
        float age = (float)(gstep0 - ts[idx]);
        sim = dot / fmaxf(sqrtf(ksq), 1e-12f) * powf(0.995f, age);
      }
      exs[c] = sim;
    }
  }
  __syncthreads();

  __shared__ int wix[K];
  if (tid < 64) {
    float s = (tid < m) ? exs[tid] : -INFINITY;
    int   i = (tid < m) ? clx[tid] : 0x7fffffff;
    for (int r=0;r<K;++r) {
      float bs=s; int bi=i;
      #pragma unroll
      for (int o=1;o<64;o<<=1){ float os=__shfl_xor(bs,o); int oi=__shfl_xor(bi,o);
        if (BET(os,oi,bs,bi)) { bs=os; bi=oi; } }
      if (tid==0) {
        out[OUT_SIMS + q*K + r] = bs;
        out[OUT_MASK + q*K + r] = (bs >= 0.0f) ? 1.0f : 0.0f;
        out[OUT_IDX  + q*K + r] = (float)bi;
        wix[r] = bi;
      }
      if (i == bi) s = -INFINITY;
    }
  }
  __syncthreads();
  for (int r=0;r<K;++r) {
    int fi = wix[r];
    for (int e=tid; e<ROWF; e+=256)
      out[(q*K + r)*ROWF + e] = values[(size_t)fi*ROWF + e];
  }
}

extern "C" void kernel_launch(void* const* d_in, const int* in_sizes, int n_in,
                              void* d_out, int out_size, void* d_ws, size_t ws_size,
                              hipStream_t stream) {
  const float* query  = (const float*)d_in[0];
  const float* keys   = (const float*)d_in[1];
  const float* values = (const float*)d_in[2];
  const int*   ts     = (const int*)d_in[3];
  const int*   gstep  = (const int*)d_in[4];

  float* out  = (float*)d_out;
  float* wsf  = (float*)d_ws;

  float* qn    = wsf + WS_QN;
  uint4* qF    = (uint4*)(wsf + WS_QF);
  float* psim  = wsf + WS_PSIM;
  int*   pidx  = (int*)(wsf + WS_PIDX);

  prep_q<<<16, 256, 0, stream>>>(query, qn, qF);
  gemm_topk<<<NBLK, 512, 0, stream>>>(keys, ts, gstep, qF, psim, pidx);
  merge_rescore<<<BATCH, 256, 0, stream>>>(psim, pidx, keys, qn, ts, gstep, values, out);
}